// Round 6
// baseline (358.452 us; speedup 1.0000x reference)
//
#include <hip/hip_runtime.h>

#define DDIM 1024
#define FFN_DIM 4096
#define SS 1024
#define MTOK 4096  // B*S

typedef __bf16 bf16x8 __attribute__((ext_vector_type(8)));
typedef float f32x4 __attribute__((ext_vector_type(4)));
typedef unsigned short ushort4v __attribute__((ext_vector_type(4)));
typedef unsigned short ushort8v __attribute__((ext_vector_type(8)));

__device__ __forceinline__ unsigned short f2bf(float f) {
    __bf16 h = (__bf16)f;
    return __builtin_bit_cast(unsigned short, h);
}
__device__ __forceinline__ float bf2f(unsigned short u) {
    union { unsigned u; float f; } x;
    x.u = (unsigned)u << 16;
    return x.f;
}

// attention-tile swizzle (rows of 128B): involution on bits 4-6
__device__ __forceinline__ int swz(int off) {
    return off ^ ((((off >> 7) & 7) ^ ((off >> 10) & 1)) << 4);
}
// gemm tile swizzle: XOR 16B-slot (bits 4-6) by row bits 0-2 (bits 7-9).
// 16-lane column reads land on 8 distinct slots x 2 rows = free 2-way.
__device__ __forceinline__ int gswz(int b) {
    return b ^ (((b >> 7) & 7) << 4);
}

// async global->LDS, 16B per lane. LDS dest = wave-uniform base + lane*16.
__device__ __forceinline__ void gload_lds16(const void* g, void* l) {
    __builtin_amdgcn_global_load_lds(
        (__attribute__((address_space(1))) unsigned int*)(unsigned long long)(g),
        (__attribute__((address_space(3))) unsigned int*)(l), 16, 0, 0);
}

// ---------------------------------------------------------------------------
// one fused f32->bf16 conversion pass over x, Wqkv, Wo, W1, W2 (4M float4s)
// ---------------------------------------------------------------------------
__global__ __launch_bounds__(256) void cvt_all(const float* __restrict__ x,
                                               const float* __restrict__ wqkv,
                                               const float* __restrict__ wo,
                                               const float* __restrict__ w1,
                                               const float* __restrict__ w2,
                                               unsigned short* __restrict__ xbf,
                                               unsigned short* __restrict__ wqkvb,
                                               unsigned short* __restrict__ wob,
                                               unsigned short* __restrict__ w1b,
                                               unsigned short* __restrict__ w2b) {
    int i = blockIdx.x * 256 + threadIdx.x;
    const float* src;
    unsigned short* dst;
    int off;
    if (i < 1048576)      { src = x;    dst = xbf;   off = i; }
    else if (i < 1835008) { src = wqkv; dst = wqkvb; off = i - 1048576; }
    else if (i < 2097152) { src = wo;   dst = wob;   off = i - 1835008; }
    else if (i < 3145728) { src = w1;   dst = w1b;   off = i - 2097152; }
    else                  { src = w2;   dst = w2b;   off = i - 3145728; }
    float4 v = ((const float4*)src)[off];
    ushort4v u = {f2bf(v.x), f2bf(v.y), f2bf(v.z), f2bf(v.w)};
    ((ushort4v*)dst)[off] = u;
}

// ---------------------------------------------------------------------------
// Pipelined GEMM: C[M,N] = A[M,K] @ B[N,K]^T (+bias on z==0).
// BM=256, BN=128, BK=64; 8 waves (4M x 2N), per-wave 64x64 out.
// 3-buffer LDS ring (3 x 48KB = 144KB), pipeline depth 2 K-tiles:
//   per tile: vmcnt(6) [tile t's loads landed; t+1's 6 stay in flight]
//   -> s_barrier -> issue stage(t+2) -> 12 swizzled ds_read_b128
//   -> 2 x {setprio(1) 16 MFMA setprio(0)}.
// Never drains vmcnt to 0 in the loop (T4). WAR-safe: stage(t+2) writes
// buf[(t-1)%3], whose reads all retired before the barrier just passed.
// EPI: 1 = bf16 out, 2 = relu->bf16 out. SPLITK in {1,2}, partial -> O0/O1.
// ---------------------------------------------------------------------------
template <int EPI, int SPLITK>
__global__ __launch_bounds__(512, 2) void gemm_pipe(const unsigned short* __restrict__ A,
                                                    const unsigned short* __restrict__ B,
                                                    const float* __restrict__ bias,
                                                    unsigned short* __restrict__ O0,
                                                    unsigned short* __restrict__ O1,
                                                    int M, int N, int K) {
    __shared__ char smem[3 * 49152];  // ring of {A 32KB | B 16KB}
    const int tid = threadIdx.x;
    const int wid = tid >> 6, lane = tid & 63;
    const int wm = wid >> 1, wn = wid & 1;
    const int lr = lane & 15, lkb = (lane >> 4) * 16;
    const int m0 = blockIdx.y * 256, n0 = blockIdx.x * 128;
    const int z = blockIdx.z;
    const int Kc = K / SPLITK, kb = z * Kc;
    const int NT = Kc / 64;

    f32x4 acc[4][4];
#pragma unroll
    for (int i = 0; i < 4; i++)
#pragma unroll
        for (int j = 0; j < 4; j++) acc[i][j] = (f32x4){0.f, 0.f, 0.f, 0.f};

    // stage one K-tile (A 32KB: 4 rounds; B 16KB: 2 rounds). 6 loads/thread.
    // LDS dest linear (HW adds lane*16); global source pre-swizzled.
    auto stage = [&](int buf, int t) {
        const int k0 = kb + t * 64;
        char* base = smem + buf * 49152;
#pragma unroll
        for (int q = 0; q < 4; q++) {
            int d = q * 8192 + wid * 1024 + lane * 16;
            int s = gswz(d);
            gload_lds16(A + (size_t)(m0 + (s >> 7)) * K + k0 + ((s & 127) >> 1),
                        base + q * 8192 + wid * 1024);
        }
#pragma unroll
        for (int q = 0; q < 2; q++) {
            int d = q * 8192 + wid * 1024 + lane * 16;
            int s = gswz(d);
            gload_lds16(B + (size_t)(n0 + (s >> 7)) * K + k0 + ((s & 127) >> 1),
                        base + 32768 + q * 8192 + wid * 1024);
        }
    };

    stage(0, 0);
    if (NT > 1) stage(1, 1);

    int cur = 0;
    for (int t = 0; t < NT; ++t) {
        if (t + 1 < NT) asm volatile("s_waitcnt vmcnt(6)" ::: "memory");
        else            asm volatile("s_waitcnt vmcnt(0)" ::: "memory");
        __builtin_amdgcn_s_barrier();
        __builtin_amdgcn_sched_barrier(0);
        if (t + 2 < NT) {
            int nxt = cur + 2;
            if (nxt >= 3) nxt -= 3;
            stage(nxt, t + 2);
        }
        const char* Ab = smem + cur * 49152;
        const char* Bb = Ab + 32768;
        bf16x8 bfr[4][2];
#pragma unroll
        for (int nb = 0; nb < 4; nb++)
#pragma unroll
            for (int ks = 0; ks < 2; ks++)
                bfr[nb][ks] = *(const bf16x8*)(Bb + gswz((wn * 64 + nb * 16 + lr) * 128 + ks * 64 + lkb));
#pragma unroll
        for (int half = 0; half < 2; half++) {
            bf16x8 afr[2][2];
#pragma unroll
            for (int mi = 0; mi < 2; mi++)
#pragma unroll
                for (int ks = 0; ks < 2; ks++)
                    afr[mi][ks] = *(const bf16x8*)(Ab + gswz((wm * 64 + (half * 2 + mi) * 16 + lr) * 128 + ks * 64 + lkb));
            __builtin_amdgcn_s_setprio(1);
#pragma unroll
            for (int mi = 0; mi < 2; mi++)
#pragma unroll
                for (int nb = 0; nb < 4; nb++)
#pragma unroll
                    for (int ks = 0; ks < 2; ks++)
                        acc[half * 2 + mi][nb] = __builtin_amdgcn_mfma_f32_16x16x32_bf16(
                            afr[mi][ks], bfr[nb][ks], acc[half * 2 + mi][nb], 0, 0, 0);
            __builtin_amdgcn_s_setprio(0);
        }
        cur = (cur == 2) ? 0 : cur + 1;
    }

    // epilogue: C/D layout col = lane&15, row = (lane>>4)*4 + reg
    unsigned short* Op = (SPLITK == 1 || z == 0) ? O0 : O1;
    float bv[4];
#pragma unroll
    for (int nb = 0; nb < 4; nb++) bv[nb] = (z == 0) ? bias[n0 + wn * 64 + nb * 16 + lr] : 0.f;
    const int rr = (lane >> 4) * 4;
#pragma unroll
    for (int mb = 0; mb < 4; mb++)
#pragma unroll
        for (int nb = 0; nb < 4; nb++) {
            int col = n0 + wn * 64 + nb * 16 + lr;
#pragma unroll
            for (int r = 0; r < 4; r++) {
                int row = m0 + wm * 64 + mb * 16 + rr + r;
                float v = acc[mb][nb][r] + bv[nb];
                if (EPI == 2) v = fmaxf(v, 0.f);
                Op[(size_t)row * N + col] = f2bf(v);
            }
        }
}

// ---------------------------------------------------------------------------
// V transpose: qkv V-part [b,s,h,d] -> vt [b,h,d,s]  (bf16)
// ---------------------------------------------------------------------------
__global__ __launch_bounds__(256) void vtrans(const unsigned short* __restrict__ qkv,
                                              unsigned short* __restrict__ vt) {
    __shared__ unsigned short T[64 * 64];
    const int tid = threadIdx.x;
    const int bh = blockIdx.y, b = bh >> 4, h = bh & 15;
    const int s0 = blockIdx.x * 64;
    const unsigned short* src = qkv + (size_t)(b * SS + s0) * 3072 + 2048 + h * 64;
#pragma unroll
    for (int p = 0; p < 2; p++) {
        int idx = p * 4096 + tid * 16;
        int row = idx >> 7, ce = (idx & 127) >> 1;
        ushort8v v = *(const ushort8v*)(src + (size_t)row * 3072 + ce);
        *(ushort8v*)((char*)T + swz(idx)) = v;
    }
    __syncthreads();
    unsigned short* dst = vt + (size_t)bh * 64 * SS + s0;
#pragma unroll
    for (int p = 0; p < 2; p++) {
        int idx = p * 4096 + tid * 16;
        int d = idx >> 7, t0 = (idx & 127) >> 1;
        ushort8v o;
#pragma unroll
        for (int i = 0; i < 8; i++)
            o[i] = *(const unsigned short*)((char*)T + swz((t0 + i) * 128 + d * 2));
        *(ushort8v*)(dst + (size_t)d * SS + t0) = o;
    }
}

// ---------------------------------------------------------------------------
// Flash attention (unchanged from round 5). XCD-grouped, log2 softmax,
// defer-max, swizzled K/V/P LDS, dbuf, 1 barrier/tile.
// ---------------------------------------------------------------------------
__global__ __launch_bounds__(256) void attn_fused(const unsigned short* __restrict__ qkv,
                                                  const unsigned short* __restrict__ vt,
                                                  const int* __restrict__ mask,
                                                  unsigned short* __restrict__ ctx) {
    __shared__ unsigned short Ksm[2][64 * 64];
    __shared__ unsigned short Vsm[2][64 * 64];
    __shared__ unsigned short Psm[4][16 * 64];
    __shared__ float maskadd[2][64];
    const int tid = threadIdx.x, wid = tid >> 6, lane = tid & 63;
    const int bid = blockIdx.x;
    const int xcd = bid & 7, loc = bid >> 3;
    const int bh = xcd * 8 + (loc >> 4), q0 = (loc & 15) * 64;
    const int b = bh >> 4, h = bh & 15;
    const int lr = lane & 15, lk2 = (lane >> 4) * 16;
    const size_t base = (size_t)b * SS * 3072 + h * 64;
    const float SC2 = 0.18033688011112042f;  // 0.125 * log2(e)

    bf16x8 qf[2];
    {
        const unsigned short* qp = qkv + base + (size_t)(q0 + wid * 16 + lr) * 3072;
        qf[0] = *(const bf16x8*)(qp + (lk2 >> 1));
        qf[1] = *(const bf16x8*)(qp + 32 + (lk2 >> 1));
    }
    float m_run[4] = {-3e38f, -3e38f, -3e38f, -3e38f};
    float l_run[4] = {0.f, 0.f, 0.f, 0.f};
    f32x4 oacc[4];
#pragma unroll
    for (int i = 0; i < 4; i++) oacc[i] = (f32x4){0.f, 0.f, 0.f, 0.f};

    const unsigned short* Kgb = qkv + base + 1024;
    const unsigned short* Vgb = vt + (size_t)bh * 64 * SS;

    auto stage = [&](int buf, int kt) {
#pragma unroll
        for (int p = 0; p < 2; p++) {
            int idx = p * 4096 + wid * 1024 + lane * 16;
            int s = swz(idx);
            int row = s >> 7, ce = (s & 127) >> 1;
            gload_lds16(Kgb + (size_t)(kt * 64 + row) * 3072 + ce,
                        (char*)Ksm[buf] + p * 4096 + wid * 1024);
            gload_lds16(Vgb + (size_t)row * SS + kt * 64 + ce,
                        (char*)Vsm[buf] + p * 4096 + wid * 1024);
        }
        if (tid < 64) maskadd[buf][tid] = mask[bh * SS + kt * 64 + tid] ? 0.f : -1.5e9f;
    };

    stage(0, 0);
    for (int kt = 0; kt < SS / 64; ++kt) {
        const int cur = kt & 1;
        __syncthreads();
        if (kt < SS / 64 - 1) stage(cur ^ 1, kt + 1);
        const char* Kb = (const char*)Ksm[cur];
        const char* Vb = (const char*)Vsm[cur];

        f32x4 sc[4];
#pragma unroll
        for (int nt = 0; nt < 4; nt++) {
            f32x4 a = (f32x4){0.f, 0.f, 0.f, 0.f};
            int rowb = (nt * 16 + lr) * 128;
            bf16x8 k0v = *(const bf16x8*)(Kb + swz(rowb + lk2));
            bf16x8 k1v = *(const bf16x8*)(Kb + swz(rowb + 64 + lk2));
            a = __builtin_amdgcn_mfma_f32_16x16x32_bf16(qf[0], k0v, a, 0, 0, 0);
            a = __builtin_amdgcn_mfma_f32_16x16x32_bf16(qf[1], k1v, a, 0, 0, 0);
            sc[nt] = a;
        }
        float mk[4];
#pragma unroll
        for (int nt = 0; nt < 4; nt++) mk[nt] = maskadd[cur][nt * 16 + lr];
        float pmax[4];
#pragma unroll
        for (int r = 0; r < 4; r++) {
            float v = -3e38f;
#pragma unroll
            for (int nt = 0; nt < 4; nt++) {
                float s = sc[nt][r] * SC2 + mk[nt];
                sc[nt][r] = s;
                v = fmaxf(v, s);
            }
            v = fmaxf(v, __shfl_xor(v, 1));
            v = fmaxf(v, __shfl_xor(v, 2));
            v = fmaxf(v, __shfl_xor(v, 4));
            v = fmaxf(v, __shfl_xor(v, 8));
            pmax[r] = v;
        }
        bool okt = true;
#pragma unroll
        for (int r = 0; r < 4; r++) okt = okt && (pmax[r] <= m_run[r] + 8.f);
        const bool skip = __all(okt);
        if (!skip) {
#pragma unroll
            for (int r = 0; r < 4; r++) {
                float mnew = fmaxf(m_run[r], pmax[r]);
                float alpha = exp2f(m_run[r] - mnew);
                m_run[r] = mnew;
                l_run[r] *= alpha;
#pragma unroll
                for (int dt = 0; dt < 4; dt++) oacc[dt][r] *= alpha;
            }
        }
#pragma unroll
        for (int r = 0; r < 4; r++) {
            float ls = 0.f;
#pragma unroll
            for (int nt = 0; nt < 4; nt++) {
                float pexp = exp2f(sc[nt][r] - m_run[r]);
                sc[nt][r] = pexp;
                ls += pexp;
            }
            ls += __shfl_xor(ls, 1);
            ls += __shfl_xor(ls, 2);
            ls += __shfl_xor(ls, 4);
            ls += __shfl_xor(ls, 8);
            l_run[r] += ls;
        }
        const int prow = (lane >> 4) * 4;
        char* Pb = (char*)Psm[wid];
#pragma unroll
        for (int nt = 0; nt < 4; nt++)
#pragma unroll
            for (int r = 0; r < 4; r++)
                *(unsigned short*)(Pb + swz((prow + r) * 128 + (nt * 16 + lr) * 2)) = f2bf(sc[nt][r]);
        bf16x8 pf0 = *(const bf16x8*)(Pb + swz(lr * 128 + lk2));
        bf16x8 pf1 = *(const bf16x8*)(Pb + swz(lr * 128 + 64 + lk2));
#pragma unroll
        for (int dt = 0; dt < 4; dt++) {
            int rowb = (dt * 16 + lr) * 128;
            bf16x8 v0 = *(const bf16x8*)(Vb + swz(rowb + lk2));
            bf16x8 v1 = *(const bf16x8*)(Vb + swz(rowb + 64 + lk2));
            oacc[dt] = __builtin_amdgcn_mfma_f32_16x16x32_bf16(pf0, v0, oacc[dt], 0, 0, 0);
            oacc[dt] = __builtin_amdgcn_mfma_f32_16x16x32_bf16(pf1, v1, oacc[dt], 0, 0, 0);
        }
    }
#pragma unroll
    for (int dt = 0; dt < 4; dt++)
#pragma unroll
        for (int r = 0; r < 4; r++) {
            float v = oacc[dt][r] / l_run[r];
            int row = q0 + wid * 16 + (lane >> 4) * 4 + r;
            ctx[(size_t)(b * SS + row) * DDIM + h * 64 + dt * 16 + lr] = f2bf(v);
        }
}

// ---------------------------------------------------------------------------
// LN1: h = LN(bf2f(wp0) + bf2f(wp1) + x) -> bf16  (fused Wo splitK reduce)
// ---------------------------------------------------------------------------
__global__ __launch_bounds__(256) void resid_ln1(const unsigned short* __restrict__ wp0,
                                                 const unsigned short* __restrict__ wp1,
                                                 const float* __restrict__ x,
                                                 const float* __restrict__ gamma,
                                                 const float* __restrict__ beta,
                                                 unsigned short* __restrict__ hbf) {
    __shared__ float red[16];
    const int row = blockIdx.x, tid = threadIdx.x;
    const int wid = tid >> 6, lane = tid & 63;
    size_t off = (size_t)row * DDIM;
    ushort4v a0 = ((const ushort4v*)(wp0 + off))[tid];
    ushort4v a1 = ((const ushort4v*)(wp1 + off))[tid];
    float4 bv = ((const float4*)(x + off))[tid];
    float4 v;
    v.x = bf2f(a0[0]) + bf2f(a1[0]) + bv.x;
    v.y = bf2f(a0[1]) + bf2f(a1[1]) + bv.y;
    v.z = bf2f(a0[2]) + bf2f(a1[2]) + bv.z;
    v.w = bf2f(a0[3]) + bf2f(a1[3]) + bv.w;
    float s = v.x + v.y + v.z + v.w;
    float s2 = v.x * v.x + v.y * v.y + v.z * v.z + v.w * v.w;
#pragma unroll
    for (int o = 1; o < 64; o <<= 1) { s += __shfl_xor(s, o); s2 += __shfl_xor(s2, o); }
    if (lane == 0) { red[wid] = s; red[8 + wid] = s2; }
    __syncthreads();
    s = red[0] + red[1] + red[2] + red[3];
    s2 = red[8] + red[9] + red[10] + red[11];
    float mean = s * (1.f / 1024.f);
    float var = s2 * (1.f / 1024.f) - mean * mean;
    float rstd = rsqrtf(var + 1e-12f);
    float4 g = ((const float4*)gamma)[tid];
    float4 be = ((const float4*)beta)[tid];
    ushort4v u = {f2bf(g.x * (v.x - mean) * rstd + be.x),
                  f2bf(g.y * (v.y - mean) * rstd + be.y),
                  f2bf(g.z * (v.z - mean) * rstd + be.z),
                  f2bf(g.w * (v.w - mean) * rstd + be.w)};
    ((ushort4v*)(hbf + off))[tid] = u;
}

// ---------------------------------------------------------------------------
// LN2: out = LN(bf2f(fp0) + bf2f(fp1) + bf2f(h)) -> f32 (fused FFN2 reduce)
// ---------------------------------------------------------------------------
__global__ __launch_bounds__(256) void resid_ln2(const unsigned short* __restrict__ fp0,
                                                 const unsigned short* __restrict__ fp1,
                                                 const unsigned short* __restrict__ hbf,
                                                 const float* __restrict__ gamma,
                                                 const float* __restrict__ beta,
                                                 float* __restrict__ out) {
    __shared__ float red[16];
    const int row = blockIdx.x, tid = threadIdx.x;
    const int wid = tid >> 6, lane = tid & 63;
    size_t off = (size_t)row * DDIM;
    ushort4v a0 = ((const ushort4v*)(fp0 + off))[tid];
    ushort4v a1 = ((const ushort4v*)(fp1 + off))[tid];
    ushort4v hv = ((const ushort4v*)(hbf + off))[tid];
    float4 v;
    v.x = bf2f(a0[0]) + bf2f(a1[0]) + bf2f(hv[0]);
    v.y = bf2f(a0[1]) + bf2f(a1[1]) + bf2f(hv[1]);
    v.z = bf2f(a0[2]) + bf2f(a1[2]) + bf2f(hv[2]);
    v.w = bf2f(a0[3]) + bf2f(a1[3]) + bf2f(hv[3]);
    float s = v.x + v.y + v.z + v.w;
    float s2 = v.x * v.x + v.y * v.y + v.z * v.z + v.w * v.w;
#pragma unroll
    for (int o = 1; o < 64; o <<= 1) { s += __shfl_xor(s, o); s2 += __shfl_xor(s2, o); }
    if (lane == 0) { red[wid] = s; red[8 + wid] = s2; }
    __syncthreads();
    s = red[0] + red[1] + red[2] + red[3];
    s2 = red[8] + red[9] + red[10] + red[11];
    float mean = s * (1.f / 1024.f);
    float var = s2 * (1.f / 1024.f) - mean * mean;
    float rstd = rsqrtf(var + 1e-12f);
    float4 g = ((const float4*)gamma)[tid];
    float4 be = ((const float4*)beta)[tid];
    float4 o;
    o.x = g.x * (v.x - mean) * rstd + be.x;
    o.y = g.y * (v.y - mean) * rstd + be.y;
    o.z = g.z * (v.z - mean) * rstd + be.z;
    o.w = g.w * (v.w - mean) * rstd + be.w;
    ((float4*)(out + off))[tid] = o;
}

// ---------------------------------------------------------------------------
extern "C" void kernel_launch(void* const* d_in, const int* in_sizes, int n_in,
                              void* d_out, int out_size, void* d_ws, size_t ws_size,
                              hipStream_t stream) {
    const float* x    = (const float*)d_in[0];
    const int*   mask = (const int*)d_in[1];
    const float* Wqkv = (const float*)d_in[2];
    const float* bqkv = (const float*)d_in[3];
    const float* Wo   = (const float*)d_in[4];
    const float* bo   = (const float*)d_in[5];
    const float* W1   = (const float*)d_in[6];
    const float* b1   = (const float*)d_in[7];
    const float* W2   = (const float*)d_in[8];
    const float* b2   = (const float*)d_in[9];
    const float* g1   = (const float*)d_in[10];
    const float* be1  = (const float*)d_in[11];
    const float* g2   = (const float*)d_in[12];
    const float* be2  = (const float*)d_in[13];
    float* out = (float*)d_out;

    // workspace (64 MB, lifetime-overlapped):
    // [0,8)   xbf -> vtb -> ff1[0:8)
    // [8,32)  qkvbf -> wp0[8,16) wp1[16,24) -> ff1[8:32)
    // [32,38) wqkvb + [38,40) wob -> hbf [32,40)
    // [40,48) w1b -> fp0
    // [48,56) w2b
    // [56,64) ctx -> fp1
    char* ws = (char*)d_ws;
    unsigned short* xbf   = (unsigned short*)(ws + 0);
    unsigned short* vtb   = (unsigned short*)(ws + 0);
    unsigned short* ff1   = (unsigned short*)(ws + 0);
    unsigned short* qkvbf = (unsigned short*)(ws + (8ull << 20));
    unsigned short* wp0   = (unsigned short*)(ws + (8ull << 20));
    unsigned short* wp1   = (unsigned short*)(ws + (16ull << 20));
    unsigned short* wqkvb = (unsigned short*)(ws + (32ull << 20));
    unsigned short* hbf   = (unsigned short*)(ws + (32ull << 20));
    unsigned short* wob   = (unsigned short*)(ws + (38ull << 20));
    unsigned short* w1b   = (unsigned short*)(ws + (40ull << 20));
    unsigned short* fp0   = (unsigned short*)(ws + (40ull << 20));
    unsigned short* w2b   = (unsigned short*)(ws + (48ull << 20));
    unsigned short* ctx   = (unsigned short*)(ws + (56ull << 20));
    unsigned short* fp1   = (unsigned short*)(ws + (56ull << 20));

    cvt_all<<<16384, 256, 0, stream>>>(x, Wqkv, Wo, W1, W2, xbf, wqkvb, wob, w1b, w2b);

    // qkv = x @ Wqkv^T + bqkv -> bf16 [4096, 3072]
    gemm_pipe<1, 1><<<dim3(24, 16, 1), 512, 0, stream>>>(xbf, wqkvb, bqkv, qkvbf, qkvbf,
                                                         MTOK, 3072, 1024);
    vtrans<<<dim3(16, 64), 256, 0, stream>>>(qkvbf, vtb);
    attn_fused<<<1024, 256, 0, stream>>>(qkvbf, vtb, mask, ctx);
    // attn_out partials (splitK2) = ctx @ Wo^T (+bo on z0) -> bf16
    gemm_pipe<1, 2><<<dim3(8, 16, 2), 512, 0, stream>>>(ctx, wob, bo, wp0, wp1,
                                                        MTOK, 1024, 1024);
    // h = LN(wp0 + wp1 + x) -> bf16
    resid_ln1<<<4096, 256, 0, stream>>>(wp0, wp1, x, g1, be1, hbf);
    // ff1 = relu(h @ W1^T + b1) -> bf16 [4096, 4096]
    gemm_pipe<2, 1><<<dim3(32, 16, 1), 512, 0, stream>>>(hbf, w1b, b1, ff1, ff1,
                                                         MTOK, FFN_DIM, 1024);
    // ff2 partials (splitK2) = ff1 @ W2^T (+b2 on z0) -> bf16
    gemm_pipe<1, 2><<<dim3(8, 16, 2), 512, 0, stream>>>(ff1, w2b, b2, fp0, fp1,
                                                        MTOK, DDIM, FFN_DIM);
    // out = LN(fp0 + fp1 + h)
    resid_ln2<<<4096, 256, 0, stream>>>(fp0, fp1, hbf, g2, be2, out);
}